// Round 6
// baseline (452.593 us; speedup 1.0000x reference)
//
#include <hip/hip_runtime.h>
#include <math.h>

// Problem constants
#define B      2048
#define N      100000
#define NPAD   100096   // 782 * 128
#define NTILES 782
#define JT     8        // j-tiles per gemm_filter block
#define DD     64
#define HH     256
#define KK     20
#define SAMPLE 4096
#define CAP    1536
#define SSEL   512
#define SLACK  1.5f
#define LCAP   16       // per-row LDS bucket slots (accumulated over JT tiles)

#define INF_F (__builtin_inff())

typedef __bf16 bf16x8 __attribute__((ext_vector_type(8)));
typedef __bf16 bf16x4 __attribute__((ext_vector_type(4)));
typedef float  floatx4 __attribute__((ext_vector_type(4)));
union U16 { uint4 u; bf16x8 v; };

__device__ __forceinline__ float wsum64(float v) {
    #pragma unroll
    for (int o = 32; o > 0; o >>= 1) v += __shfl_xor(v, o, 64);
    return v;
}

// ---------------------------------------------------------------- prep ------
__global__ __launch_bounds__(64) void prep_kernel(const float* __restrict__ z,
                                                  float* __restrict__ xs,
                                                  float* __restrict__ xnorm,
                                                  __bf16* __restrict__ xs_h,
                                                  int* __restrict__ cnt) {
    int b = blockIdx.x, d = threadIdx.x;
    float v = z[b * 66 + d];
    xs[b * 64 + d] = v;
    xs_h[b * 64 + d] = (__bf16)v;
    float s = wsum64(v * v);
    if (d == 0) xnorm[b] = s;
    if (d == 1) cnt[b] = 0;
}

// ------------------------------------------------- dnorm + bf16 convert -----
__global__ __launch_bounds__(256) void data_prep(const float* __restrict__ data,
                                                 float* __restrict__ dnorm,
                                                 __bf16* __restrict__ d_hi) {
    int gt = blockIdx.x * 256 + threadIdx.x;
    int j = gt >> 4;
    int l = gt & 15;
    if (j >= NPAD) return;
    float4 v = make_float4(0.f, 0.f, 0.f, 0.f);
    if (j < N)
        v = reinterpret_cast<const float4*>(data + (size_t)j * 64)[l];
    bf16x4 o;
    o.x = (__bf16)v.x; o.y = (__bf16)v.y; o.z = (__bf16)v.z; o.w = (__bf16)v.w;
    *reinterpret_cast<bf16x4*>(d_hi + (size_t)j * 64 + l * 4) = o;
    float s = v.x * v.x + v.y * v.y + v.z * v.z + v.w * v.w;
    #pragma unroll
    for (int o2 = 1; o2 < 16; o2 <<= 1) s += __shfl_xor(s, o2, 64);
    if (l == 0 && j < N) dnorm[j] = s;
}

// ------------------------------------------------ exact sample dist GEMM ----
__global__ __launch_bounds__(256) void sample_gemm(const float* __restrict__ data,
                                                   const float* __restrict__ xs,
                                                   const float* __restrict__ xnorm,
                                                   const float* __restrict__ dnorm,
                                                   float* __restrict__ samp) {
    __shared__ float sx[64][64];
    __shared__ float sd[64][128];
    int tid = threadIdx.x;
    int row0 = blockIdx.x * 64;
    int j0 = blockIdx.y * 128;
    #pragma unroll
    for (int p = 0; p < 4; ++p) {
        int flat = p * 256 + tid;
        int m = flat & 63, k4 = flat >> 6;
        float4 v = *reinterpret_cast<const float4*>(xs + (row0 + m) * 64 + k4 * 4);
        sx[k4 * 4 + 0][m] = v.x; sx[k4 * 4 + 1][m] = v.y;
        sx[k4 * 4 + 2][m] = v.z; sx[k4 * 4 + 3][m] = v.w;
    }
    #pragma unroll
    for (int p = 0; p < 8; ++p) {
        int flat = p * 256 + tid;
        int n = flat & 127, k4 = flat >> 7;
        float4 v = *reinterpret_cast<const float4*>(data + (size_t)(j0 + n) * 64 + k4 * 4);
        sd[k4 * 4 + 0][n] = v.x; sd[k4 * 4 + 1][n] = v.y;
        sd[k4 * 4 + 2][n] = v.z; sd[k4 * 4 + 3][n] = v.w;
    }
    __syncthreads();

    int tx = tid & 15, ty = tid >> 4;
    int m0 = ty * 4, n0 = tx * 8;
    float acc[4][8];
    #pragma unroll
    for (int r = 0; r < 4; ++r)
        #pragma unroll
        for (int c = 0; c < 8; ++c) acc[r][c] = 0.f;
    #pragma unroll 8
    for (int k = 0; k < 64; ++k) {
        float4 a  = *reinterpret_cast<const float4*>(&sx[k][m0]);
        float4 b0 = *reinterpret_cast<const float4*>(&sd[k][n0]);
        float4 b1 = *reinterpret_cast<const float4*>(&sd[k][n0 + 4]);
        float av[4] = {a.x, a.y, a.z, a.w};
        float bv[8] = {b0.x, b0.y, b0.z, b0.w, b1.x, b1.y, b1.z, b1.w};
        #pragma unroll
        for (int r = 0; r < 4; ++r)
            #pragma unroll
            for (int c = 0; c < 8; ++c)
                acc[r][c] = fmaf(av[r], bv[c], acc[r][c]);
    }
    #pragma unroll
    for (int r = 0; r < 4; ++r) {
        int row = row0 + m0 + r;
        float xn = xnorm[row];
        #pragma unroll
        for (int c = 0; c < 8; ++c) {
            int j = j0 + n0 + c;
            samp[(size_t)row * SAMPLE + j] = xn + dnorm[j] - 2.0f * acc[r][c];
        }
    }
}

// ------------------------------------------- thr select via radix-select ----
// thr[row] = 20th smallest of 4096 sampled sq (radix on clamped float bits;
// clamp-to-0 can only raise the threshold -> still a valid upper bound)
__global__ __launch_bounds__(256) void thr_select(const float* __restrict__ samp,
                                                  float* __restrict__ thr) {
    __shared__ unsigned keys[SAMPLE];
    __shared__ int hist[256];
    __shared__ int s_bin, s_rank;
    int row = blockIdx.x, tid = threadIdx.x;
    for (int i = tid; i < SAMPLE; i += 256) {
        float v = samp[(size_t)row * SAMPLE + i];
        keys[i] = __float_as_uint(fmaxf(v, 0.f));
    }
    int rank = KK - 1;
    unsigned prefix = 0, pmask = 0;
    for (int round = 0; round < 4; ++round) {
        int shift = 24 - 8 * round;
        hist[tid] = 0;
        __syncthreads();
        for (int i = tid; i < SAMPLE; i += 256) {
            unsigned k = keys[i];
            if ((k & pmask) == prefix) atomicAdd(&hist[(k >> shift) & 255], 1);
        }
        __syncthreads();
        if (tid == 0) {
            int cum = 0, b = 0;
            for (; b < 256; ++b) { int c = hist[b]; if (cum + c > rank) break; cum += c; }
            s_bin = b; s_rank = rank - cum;
        }
        __syncthreads();
        prefix |= ((unsigned)s_bin) << shift;
        pmask  |= 0xFFu << shift;
        rank = s_rank;
    }
    if (tid == 0) thr[row] = __uint_as_float(prefix);
}

// --------------------------------------- bf16 MFMA filter, JT-pipelined -----
__global__ __launch_bounds__(256) void gemm_filter(const __bf16* __restrict__ xs_h,
                                                   const __bf16* __restrict__ d_hi,
                                                   const float* __restrict__ xnorm,
                                                   const float* __restrict__ dnorm,
                                                   const float* __restrict__ thr,
                                                   int* __restrict__ cnt,
                                                   float* __restrict__ bufd,
                                                   int* __restrict__ bufi) {
    __shared__ uint4 sA[8][128];
    __shared__ uint4 sB[8][128];
    __shared__ float sXN[128], sLIM[128];
    __shared__ int   lcnt[128];
    __shared__ float lbd[128][LCAP];
    __shared__ int   lbj[128][LCAP];
    int tid = threadIdx.x;
    int m0 = blockIdx.x * 128;
    int tile0 = blockIdx.y * JT;
    int ntile = NTILES - tile0; if (ntile > JT) ntile = JT;

    #pragma unroll
    for (int p = 0; p < 4; ++p) {
        int flat = p * 256 + tid;
        int m = flat & 127, c = flat >> 7;
        sA[c][m] = reinterpret_cast<const uint4*>(xs_h + (size_t)(m0 + m) * 64)[c];
    }
    if (tid < 128) {
        float xn = xnorm[m0 + tid];
        sXN[tid] = xn;
        sLIM[tid] = thr[m0 + tid] + SLACK - xn;   // pass <=> dn - 2*acc <= sLIM
        lcnt[tid] = 0;
    }

    int wv = tid >> 6;
    int wm = wv & 1, wn = wv >> 1;
    int lane = tid & 63;
    int l16 = lane & 15, quad = lane >> 4;

    __syncthreads();
    float slim[4][4], sxnr[4][4];
    #pragma unroll
    for (int mt = 0; mt < 4; ++mt)
        #pragma unroll
        for (int rg = 0; rg < 4; ++rg) {
            int mloc = wm * 64 + mt * 16 + quad * 4 + rg;
            slim[mt][rg] = sLIM[mloc];
            sxnr[mt][rg] = sXN[mloc];
        }

    uint4 breg[4];
    float dnr[4];
    // prefetch tile 0
    {
        int jb = tile0 * 128;
        #pragma unroll
        for (int p = 0; p < 4; ++p) {
            int flat = p * 256 + tid;
            int n = flat & 127, c = flat >> 7;
            breg[p] = reinterpret_cast<const uint4*>(d_hi + (size_t)(jb + n) * 64)[c];
        }
        #pragma unroll
        for (int nt = 0; nt < 4; ++nt) {
            int jn = jb + wn * 64 + nt * 16 + l16;
            dnr[nt] = dnorm[jn < N ? jn : N - 1];
        }
    }

    for (int t = 0; t < ntile; ++t) {
        __syncthreads();
        #pragma unroll
        for (int p = 0; p < 4; ++p) {
            int flat = p * 256 + tid;
            int n = flat & 127, c = flat >> 7;
            sB[c][n] = breg[p];
        }
        int jbase = (tile0 + t) * 128;
        float dncur[4];
        #pragma unroll
        for (int nt = 0; nt < 4; ++nt) dncur[nt] = dnr[nt];
        __syncthreads();
        if (t + 1 < ntile) {              // prefetch next tile (overlaps MFMA)
            int jb = jbase + 128;
            #pragma unroll
            for (int p = 0; p < 4; ++p) {
                int flat = p * 256 + tid;
                int n = flat & 127, c = flat >> 7;
                breg[p] = reinterpret_cast<const uint4*>(d_hi + (size_t)(jb + n) * 64)[c];
            }
            #pragma unroll
            for (int nt = 0; nt < 4; ++nt) {
                int jn = jb + wn * 64 + nt * 16 + l16;
                dnr[nt] = dnorm[jn < N ? jn : N - 1];
            }
        }

        floatx4 acc[4][4];
        #pragma unroll
        for (int mt = 0; mt < 4; ++mt)
            #pragma unroll
            for (int nt = 0; nt < 4; ++nt)
                acc[mt][nt] = (floatx4){0.f, 0.f, 0.f, 0.f};
        #pragma unroll
        for (int s = 0; s < 2; ++s) {
            bf16x8 af[4], bfr[4];
            #pragma unroll
            for (int mt = 0; mt < 4; ++mt) {
                U16 u; u.u = sA[s * 4 + quad][wm * 64 + mt * 16 + l16]; af[mt] = u.v;
            }
            #pragma unroll
            for (int nt = 0; nt < 4; ++nt) {
                U16 u; u.u = sB[s * 4 + quad][wn * 64 + nt * 16 + l16]; bfr[nt] = u.v;
            }
            #pragma unroll
            for (int mt = 0; mt < 4; ++mt)
                #pragma unroll
                for (int nt = 0; nt < 4; ++nt)
                    acc[mt][nt] = __builtin_amdgcn_mfma_f32_16x16x32_bf16(
                        af[mt], bfr[nt], acc[mt][nt], 0, 0, 0);
        }

        #pragma unroll
        for (int nt = 0; nt < 4; ++nt) {
            int nloc = wn * 64 + nt * 16 + l16;
            int j = jbase + nloc;
            bool jv = (j < N);
            float dn = dncur[nt];
            #pragma unroll
            for (int mt = 0; mt < 4; ++mt) {
                floatx4 a4 = acc[mt][nt];
                float t0 = fmaf(a4[0], -2.f, dn), t1 = fmaf(a4[1], -2.f, dn);
                float t2 = fmaf(a4[2], -2.f, dn), t3 = fmaf(a4[3], -2.f, dn);
                bool p0 = t0 <= slim[mt][0], p1 = t1 <= slim[mt][1];
                bool p2 = t2 <= slim[mt][2], p3 = t3 <= slim[mt][3];
                if (jv && (p0 | p1 | p2 | p3)) {
                    #pragma unroll
                    for (int rg = 0; rg < 4; ++rg) {
                        float tv = (rg == 0) ? t0 : (rg == 1) ? t1 : (rg == 2) ? t2 : t3;
                        bool pp  = (rg == 0) ? p0 : (rg == 1) ? p1 : (rg == 2) ? p2 : p3;
                        if (pp) {
                            int mloc = wm * 64 + mt * 16 + quad * 4 + rg;
                            int pos = atomicAdd(&lcnt[mloc], 1);
                            float sqb = tv + sxnr[mt][rg];
                            if (pos < LCAP) {
                                lbd[mloc][pos] = sqb;
                                lbj[mloc][pos] = j;
                            } else {                       // rare overflow
                                int row = m0 + mloc;
                                int gp = atomicAdd(&cnt[row], 1);
                                if (gp < CAP) {
                                    bufd[(size_t)row * CAP + gp] = sqb;
                                    bufi[(size_t)row * CAP + gp] = j;
                                }
                            }
                        }
                    }
                }
            }
        }
    }
    __syncthreads();
    if (tid < 128) {
        int c = lcnt[tid];
        if (c > LCAP) c = LCAP;
        if (c > 0) {
            int row = m0 + tid;
            int base = atomicAdd(&cnt[row], c);
            for (int i = 0; i < c; ++i) {
                int gp = base + i;
                if (gp < CAP) {
                    bufd[(size_t)row * CAP + gp] = lbd[tid][i];
                    bufi[(size_t)row * CAP + gp] = lbj[tid][i];
                }
            }
        }
    }
}

// ------------------------------- select + MLP + metrics (fused finish) ------
__global__ __launch_bounds__(64) void select_finish(const float* __restrict__ bufd,
                                                    const int* __restrict__ bufi,
                                                    const int* __restrict__ cnt,
                                                    const float* __restrict__ xs,
                                                    const float* __restrict__ xnorm,
                                                    const float* __restrict__ dnorm,
                                                    const float* __restrict__ data,
                                                    const float* __restrict__ vel,
                                                    const float* __restrict__ tp,
                                                    const float* __restrict__ W1,
                                                    const float* __restrict__ b1,
                                                    const float* __restrict__ W2,
                                                    const float* __restrict__ b2,
                                                    float* __restrict__ out) {
    __shared__ float sd[CAP];
    __shared__ int   si[CAP];
    __shared__ float sx[64];
    __shared__ float shid[HH];
    __shared__ float se[SSEL];
    __shared__ int   sj[SSEL];
    __shared__ int   hist[256];
    __shared__ int   s_bin, s_rank, scnt;
    __shared__ float seld[KK];
    __shared__ int   seli[KK];
    __shared__ float selw[KK];
    int row = blockIdx.x, lane = threadIdx.x;
    int n = cnt[row];
    if (n > CAP) n = CAP;
    for (int i = lane; i < n; i += 64) {
        sd[i] = bufd[(size_t)row * CAP + i];
        si[i] = bufi[(size_t)row * CAP + i];
    }
    sx[lane] = xs[row * 64 + lane];
    if (lane == 0) scnt = 0;
    __syncthreads();

    // ---- fused MLP: xd = relu([x,t]@W1+b1)@W2+b2 (same fmaf order as before)
    float tv = tp[0];
    float a0 = b1[lane], a1 = b1[lane + 64], a2 = b1[lane + 128], a3 = b1[lane + 192];
    for (int i = 0; i < 64; ++i) {
        float xi = sx[i];
        a0 = fmaf(xi, W1[i * HH + lane], a0);
        a1 = fmaf(xi, W1[i * HH + lane + 64], a1);
        a2 = fmaf(xi, W1[i * HH + lane + 128], a2);
        a3 = fmaf(xi, W1[i * HH + lane + 192], a3);
    }
    a0 = fmaf(tv, W1[64 * HH + lane], a0);
    a1 = fmaf(tv, W1[64 * HH + lane + 64], a1);
    a2 = fmaf(tv, W1[64 * HH + lane + 128], a2);
    a3 = fmaf(tv, W1[64 * HH + lane + 192], a3);
    shid[lane] = fmaxf(a0, 0.f);
    shid[lane + 64] = fmaxf(a1, 0.f);
    shid[lane + 128] = fmaxf(a2, 0.f);
    shid[lane + 192] = fmaxf(a3, 0.f);
    __syncthreads();
    float xd = b2[lane];
    for (int h = 0; h < HH; ++h)
        xd = fmaf(shid[h], W2[h * 64 + lane], xd);

    // ---- radix-select: T = 20th smallest approx sq in bucket
    int rank = KK - 1;
    unsigned prefix = 0, pmask = 0;
    for (int round = 0; round < 4; ++round) {
        int shift = 24 - 8 * round;
        for (int i = lane; i < 256; i += 64) hist[i] = 0;
        __syncthreads();
        for (int i = lane; i < n; i += 64) {
            unsigned k = __float_as_uint(fmaxf(sd[i], 0.f));
            if ((k & pmask) == prefix) atomicAdd(&hist[(k >> shift) & 255], 1);
        }
        __syncthreads();
        if (lane == 0) {
            int cum = 0, b = 0;
            for (; b < 256; ++b) { int c = hist[b]; if (cum + c > rank) break; cum += c; }
            s_bin = b; s_rank = rank - cum;
        }
        __syncthreads();
        prefix |= ((unsigned)s_bin) << shift;
        pmask  |= 0xFFu << shift;
        rank = s_rank;
    }
    float T = __uint_as_float(prefix);

    // ---- gather recompute band {approx <= T + 2*SLACK} (superset of top-20)
    for (int i = lane; i < n; i += 64) {
        if (sd[i] <= T + 2.0f * SLACK) {
            int q = atomicAdd(&scnt, 1);
            if (q < SSEL) sj[q] = si[i];
        }
    }
    __syncthreads();
    int m = scnt < SSEL ? scnt : SSEL;
    // exact fp32 recompute (bit-identical chain)
    for (int c = lane; c < m; c += 64) {
        int j = sj[c];
        const float4* dp = reinterpret_cast<const float4*>(data + (size_t)j * 64);
        float dot = 0.f;
        #pragma unroll
        for (int kb = 0; kb < 16; ++kb) {
            float4 q = dp[kb];
            dot = fmaf(sx[kb * 4 + 0], q.x, dot);
            dot = fmaf(sx[kb * 4 + 1], q.y, dot);
            dot = fmaf(sx[kb * 4 + 2], q.z, dot);
            dot = fmaf(sx[kb * 4 + 3], q.w, dot);
        }
        se[c] = xnorm[row] + dnorm[j] - 2.0f * dot;
    }
    __syncthreads();
    // exact top-20, tie-break smaller index (matches lax.top_k)
    for (int k = 0; k < KK; ++k) {
        float v = INF_F; int id = 0x7fffffff; int p = -1;
        for (int i = lane; i < m; i += 64) {
            float x = se[i]; int xi = sj[i];
            if (x < v || (x == v && xi < id)) { v = x; id = xi; p = i; }
        }
        #pragma unroll
        for (int o = 32; o > 0; o >>= 1) {
            float ov = __shfl_xor(v, o, 64);
            int oid = __shfl_xor(id, o, 64);
            int op  = __shfl_xor(p, o, 64);
            if (ov < v || (ov == v && oid < id)) { v = ov; id = oid; p = op; }
        }
        if (lane == 0) {
            seld[k] = v; seli[k] = id;
            if (p >= 0) se[p] = INF_F;
        }
        __syncthreads();
    }
    float d20 = sqrtf(fmaxf(seld[KK - 1], 1e-30f));
    float h = fmaxf(d20, 1e-12f);
    float wk = 0.f;
    if (lane < KK) {
        float dd = sqrtf(fmaxf(seld[lane], 1e-30f));
        wk = expf(-(dd * dd) / (2.f * h * h));
    }
    float tot = wsum64(wk) + 1e-12f;
    if (lane < KK) selw[lane] = wk / tot;
    __syncthreads();
    float u = 0.f;
    #pragma unroll
    for (int k = 0; k < KK; ++k)
        u = fmaf(selw[k], vel[(size_t)seli[k] * 64 + lane], u);
    float du  = wsum64(u * xd);
    float nu2 = wsum64(u * u);
    float nx2 = wsum64(xd * xd);
    float l2  = wsum64((u - xd) * (u - xd));
    float nu = fmaxf(sqrtf(nu2), 1e-8f);
    float nx = fmaxf(sqrtf(nx2), 1e-8f);
    out[(size_t)row * 66 + lane] = xd;
    if (lane == 0) {
        out[(size_t)row * 66 + 64] = 1.f - du / (nu * nx);
        out[(size_t)row * 66 + 65] = l2;
    }
}

// ---------------------------------------------------------------------------
extern "C" void kernel_launch(void* const* d_in, const int* in_sizes, int n_in,
                              void* d_out, int out_size, void* d_ws, size_t ws_size,
                              hipStream_t stream) {
    const float* t_   = (const float*)d_in[0];
    const float* z    = (const float*)d_in[1];
    const float* data = (const float*)d_in[2];
    const float* vel  = (const float*)d_in[3];
    const float* W1   = (const float*)d_in[4];
    const float* b1   = (const float*)d_in[5];
    const float* W2   = (const float*)d_in[6];
    const float* b2   = (const float*)d_in[7];
    float* out = (float*)d_out;

    // workspace layout (floats, 16B-aligned); total ~47.6 MB
    float*  xs    = (float*)d_ws;                     // 131072
    float*  xnorm = xs + 131072;                      // 2048
    float*  thr   = xnorm + 2048;                     // 2048
    int*    cnt   = (int*)(thr + 2048);               // 2048
    float*  dnorm = (float*)(cnt + 2048);             // 100096
    __bf16* xs_h  = (__bf16*)(dnorm + 100096);        // 131072 bf16
    __bf16* d_hi  = xs_h + 131072;                    // NPAD*64 bf16
    float*  samp  = (float*)(d_hi + (size_t)NPAD * 64);  // 2048*4096
    float*  bufd  = samp;                             // overlap: samp dead first
    int*    bufi  = (int*)(bufd + (size_t)B * CAP);

    prep_kernel<<<B, 64, 0, stream>>>(z, xs, xnorm, xs_h, cnt);
    data_prep<<<(NPAD * 16) / 256, 256, 0, stream>>>(data, dnorm, d_hi);
    sample_gemm<<<dim3(B / 64, SAMPLE / 128), 256, 0, stream>>>(data, xs, xnorm, dnorm, samp);
    thr_select<<<B, 256, 0, stream>>>(samp, thr);
    gemm_filter<<<dim3(B / 128, (NTILES + JT - 1) / JT), 256, 0, stream>>>(
        xs_h, d_hi, xnorm, dnorm, thr, cnt, bufd, bufi);
    select_finish<<<B, 64, 0, stream>>>(bufd, bufi, cnt, xs, xnorm, dnorm, data,
                                        vel, t_, W1, b1, W2, b2, out);
    (void)ws_size; (void)in_sizes; (void)n_in; (void)out_size;
}

// Round 7
// 374.874 us; speedup vs baseline: 1.2073x; 1.2073x over previous
//
#include <hip/hip_runtime.h>
#include <math.h>

// Problem constants
#define B      2048
#define N      100000
#define NPAD   100096   // 782 * 128
#define NTILES 782
#define JT2    16       // j-tiles per gemm_filter block; 49 * 16 = 784 >= 782
#define DD     64
#define HH     256
#define KK     20
#define SAMPLE 4096
#define CAP    1536
#define SSEL   512
#define SLACK  1.5f
#define LCAP   32       // per-row LDS bucket slots (lambda ~12 over 16 tiles)

#define INF_F (__builtin_inff())

typedef __bf16 bf16x8 __attribute__((ext_vector_type(8)));
typedef __bf16 bf16x4 __attribute__((ext_vector_type(4)));
typedef float  floatx4 __attribute__((ext_vector_type(4)));
union U16 { uint4 u; bf16x8 v; };

__device__ __forceinline__ float wsum64(float v) {
    #pragma unroll
    for (int o = 32; o > 0; o >>= 1) v += __shfl_xor(v, o, 64);
    return v;
}

// ---------------------------------------------------------------- prep ------
__global__ __launch_bounds__(64) void prep_kernel(const float* __restrict__ z,
                                                  float* __restrict__ xs,
                                                  float* __restrict__ xnorm,
                                                  __bf16* __restrict__ xs_h,
                                                  int* __restrict__ cnt) {
    int b = blockIdx.x, d = threadIdx.x;
    float v = z[b * 66 + d];
    xs[b * 64 + d] = v;
    xs_h[b * 64 + d] = (__bf16)v;
    float s = wsum64(v * v);
    if (d == 0) xnorm[b] = s;
    if (d == 1) cnt[b] = 0;
}

// ------------------------------------------------- dnorm + bf16 convert -----
__global__ __launch_bounds__(256) void data_prep(const float* __restrict__ data,
                                                 float* __restrict__ dnorm,
                                                 __bf16* __restrict__ d_hi) {
    int gt = blockIdx.x * 256 + threadIdx.x;
    int j = gt >> 4;
    int l = gt & 15;
    if (j >= NPAD) return;
    float4 v = make_float4(0.f, 0.f, 0.f, 0.f);
    if (j < N)
        v = reinterpret_cast<const float4*>(data + (size_t)j * 64)[l];
    bf16x4 o;
    o.x = (__bf16)v.x; o.y = (__bf16)v.y; o.z = (__bf16)v.z; o.w = (__bf16)v.w;
    *reinterpret_cast<bf16x4*>(d_hi + (size_t)j * 64 + l * 4) = o;
    float s = v.x * v.x + v.y * v.y + v.z * v.z + v.w * v.w;
    #pragma unroll
    for (int o2 = 1; o2 < 16; o2 <<= 1) s += __shfl_xor(s, o2, 64);
    if (l == 0) dnorm[j] = (j < N) ? s : INF_F;   // pad rows can never pass
}

// ---------------------------------------------------------------- mlp -------
__global__ __launch_bounds__(256) void mlp_kernel(const float* __restrict__ z,
                                                  const float* __restrict__ tp,
                                                  const float* __restrict__ W1,
                                                  const float* __restrict__ b1,
                                                  const float* __restrict__ W2,
                                                  const float* __restrict__ b2,
                                                  float* __restrict__ xdot) {
    __shared__ float sin_[8][65];
    __shared__ float shid[8][HH];
    int tid = threadIdx.x;
    int row0 = blockIdx.x * 8;
    float tval = tp[0];
    for (int idx = tid; idx < 8 * 64; idx += 256) {
        int r = idx >> 6, d = idx & 63;
        sin_[r][d] = z[(row0 + r) * 66 + d];
    }
    if (tid < 8) sin_[tid][64] = tval;
    __syncthreads();

    int h = tid;
    float acc[8];
    #pragma unroll
    for (int r = 0; r < 8; ++r) acc[r] = b1[h];
    for (int i = 0; i < 65; ++i) {
        float wv = W1[i * HH + h];
        #pragma unroll
        for (int r = 0; r < 8; ++r) acc[r] = fmaf(sin_[r][i], wv, acc[r]);
    }
    #pragma unroll
    for (int r = 0; r < 8; ++r) shid[r][h] = fmaxf(acc[r], 0.f);
    __syncthreads();

    int d = tid & 63, rb = tid >> 6;
    for (int rr = rb; rr < 8; rr += 4) {
        float a = b2[d];
        #pragma unroll 8
        for (int hh2 = 0; hh2 < HH; ++hh2)
            a = fmaf(shid[rr][hh2], W2[hh2 * 64 + d], a);
        xdot[(size_t)(row0 + rr) * 64 + d] = a;
    }
}

// --------------------------- approx sample GEMM (MFMA, register-direct) -----
// writes approx sq for j in [0,4096) densely; threshold derived from these is
// widened by 2*SLACK downstream, so approx is safe.
__global__ __launch_bounds__(256) void sample_gemm(const __bf16* __restrict__ xs_h,
                                                   const __bf16* __restrict__ d_hi,
                                                   const float* __restrict__ xnorm,
                                                   const float* __restrict__ dnorm,
                                                   float* __restrict__ samp) {
    int tid = threadIdx.x;
    int m0 = blockIdx.x * 128;
    int jbase = blockIdx.y * 128;
    int wv = tid >> 6, wm = wv & 1, wn = wv >> 1;
    int lane = tid & 63, l16 = lane & 15, quad = lane >> 4;

    bf16x8 af[2][4], bfr[2][4];
    #pragma unroll
    for (int s = 0; s < 2; ++s)
        #pragma unroll
        for (int mt = 0; mt < 4; ++mt) {
            int row = m0 + wm * 64 + mt * 16 + l16;
            U16 u; u.u = reinterpret_cast<const uint4*>(xs_h + (size_t)row * 64)[s * 4 + quad];
            af[s][mt] = u.v;
        }
    #pragma unroll
    for (int s = 0; s < 2; ++s)
        #pragma unroll
        for (int nt = 0; nt < 4; ++nt) {
            int jr = jbase + wn * 64 + nt * 16 + l16;
            U16 u; u.u = reinterpret_cast<const uint4*>(d_hi + (size_t)jr * 64)[s * 4 + quad];
            bfr[s][nt] = u.v;
        }
    float dn[4], sxn[4][4];
    #pragma unroll
    for (int nt = 0; nt < 4; ++nt)
        dn[nt] = dnorm[jbase + wn * 64 + nt * 16 + l16];
    #pragma unroll
    for (int mt = 0; mt < 4; ++mt)
        #pragma unroll
        for (int rg = 0; rg < 4; ++rg)
            sxn[mt][rg] = xnorm[m0 + wm * 64 + mt * 16 + quad * 4 + rg];

    floatx4 acc[4][4];
    #pragma unroll
    for (int mt = 0; mt < 4; ++mt)
        #pragma unroll
        for (int nt = 0; nt < 4; ++nt)
            acc[mt][nt] = (floatx4){0.f, 0.f, 0.f, 0.f};
    #pragma unroll
    for (int s = 0; s < 2; ++s)
        #pragma unroll
        for (int mt = 0; mt < 4; ++mt)
            #pragma unroll
            for (int nt = 0; nt < 4; ++nt)
                acc[mt][nt] = __builtin_amdgcn_mfma_f32_16x16x32_bf16(
                    af[s][mt], bfr[s][nt], acc[mt][nt], 0, 0, 0);

    #pragma unroll
    for (int mt = 0; mt < 4; ++mt)
        #pragma unroll
        for (int nt = 0; nt < 4; ++nt) {
            floatx4 a4 = acc[mt][nt];
            int j = jbase + wn * 64 + nt * 16 + l16;
            #pragma unroll
            for (int rg = 0; rg < 4; ++rg) {
                int row = m0 + wm * 64 + mt * 16 + quad * 4 + rg;
                samp[(size_t)row * SAMPLE + j] = fmaf(a4[rg], -2.f, dn[nt]) + sxn[mt][rg];
            }
        }
}

// ------------------------------------------- thr select via radix-select ----
// thr[row] = 20th smallest approx sample sq (clamped >=0; clamp only raises
// the threshold -> safe). Bin search parallelized across wave 0.
__global__ __launch_bounds__(256) void thr_select(const float* __restrict__ samp,
                                                  float* __restrict__ thr) {
    __shared__ unsigned keys[SAMPLE];
    __shared__ int hist[256];
    __shared__ int s_bin, s_rank;
    int row = blockIdx.x, tid = threadIdx.x;
    for (int i = tid; i < SAMPLE; i += 256)
        keys[i] = __float_as_uint(fmaxf(samp[(size_t)row * SAMPLE + i], 0.f));
    int rank = KK - 1;
    unsigned prefix = 0, pmask = 0;
    for (int round = 0; round < 4; ++round) {
        int shift = 24 - 8 * round;
        hist[tid] = 0;
        __syncthreads();
        for (int i = tid; i < SAMPLE; i += 256) {
            unsigned k = keys[i];
            if ((k & pmask) == prefix) atomicAdd(&hist[(k >> shift) & 255], 1);
        }
        __syncthreads();
        if (tid < 64) {
            int base = tid * 4;
            int h0 = hist[base], h1 = hist[base + 1], h2 = hist[base + 2], h3 = hist[base + 3];
            int s4 = h0 + h1 + h2 + h3;
            int incl = s4;
            #pragma unroll
            for (int o = 1; o < 64; o <<= 1) {
                int t = __shfl_up(incl, o, 64);
                if (tid >= o) incl += t;
            }
            int excl = incl - s4;
            if (rank >= excl && rank < incl) {
                int r = rank - excl; int b = 0;
                if (r >= h0) { r -= h0; b = 1;
                    if (r >= h1) { r -= h1; b = 2;
                        if (r >= h2) { r -= h2; b = 3; } } }
                s_bin = base + b; s_rank = r;
            }
        }
        __syncthreads();
        prefix |= ((unsigned)s_bin) << shift;
        pmask  |= 0xFFu << shift;
        rank = s_rank;
    }
    if (tid == 0) thr[row] = __uint_as_float(prefix);
}

// ----------------- bf16 MFMA filter: register-direct, barrier-free j-loop ---
// keep j iff sq_b <= thr + 2*SLACK  (covers: true top-20 has
// sq <= 20th_true_sample <= thr_approx + SLACK, and sq_b <= sq + SLACK)
__global__ __launch_bounds__(256, 3) void gemm_filter(const __bf16* __restrict__ xs_h,
                                                      const __bf16* __restrict__ d_hi,
                                                      const float* __restrict__ xnorm,
                                                      const float* __restrict__ dnorm,
                                                      const float* __restrict__ thr,
                                                      int* __restrict__ cnt,
                                                      float* __restrict__ bufd,
                                                      int* __restrict__ bufi) {
    __shared__ float sXN[128];
    __shared__ int   lcnt[128];
    __shared__ float lbd[128][LCAP];
    __shared__ int   lbj[128][LCAP];
    int tid = threadIdx.x;
    int m0 = blockIdx.x * 128;
    int t0 = blockIdx.y * JT2;
    int ntile = NTILES - t0; if (ntile > JT2) ntile = JT2;

    int wv = tid >> 6, wm = wv & 1, wn = wv >> 1;
    int lane = tid & 63, l16 = lane & 15, quad = lane >> 4;

    if (tid < 128) { sXN[tid] = xnorm[m0 + tid]; lcnt[tid] = 0; }

    // persistent A fragments (16B contiguous per lane, straight from global)
    bf16x8 af[2][4];
    #pragma unroll
    for (int s = 0; s < 2; ++s)
        #pragma unroll
        for (int mt = 0; mt < 4; ++mt) {
            int row = m0 + wm * 64 + mt * 16 + l16;
            U16 u; u.u = reinterpret_cast<const uint4*>(xs_h + (size_t)row * 64)[s * 4 + quad];
            af[s][mt] = u.v;
        }
    float slim[4][4];
    #pragma unroll
    for (int mt = 0; mt < 4; ++mt)
        #pragma unroll
        for (int rg = 0; rg < 4; ++rg) {
            int mloc = wm * 64 + mt * 16 + quad * 4 + rg;
            slim[mt][rg] = thr[m0 + mloc] + 2.0f * SLACK - xnorm[m0 + mloc];
        }
    __syncthreads();

    for (int t = 0; t < ntile; ++t) {
        int jbase = (t0 + t) * 128;
        bf16x8 bfr[2][4];
        #pragma unroll
        for (int s = 0; s < 2; ++s)
            #pragma unroll
            for (int nt = 0; nt < 4; ++nt) {
                int jr = jbase + wn * 64 + nt * 16 + l16;
                U16 u; u.u = reinterpret_cast<const uint4*>(d_hi + (size_t)jr * 64)[s * 4 + quad];
                bfr[s][nt] = u.v;
            }
        float dn[4];
        #pragma unroll
        for (int nt = 0; nt < 4; ++nt)
            dn[nt] = dnorm[jbase + wn * 64 + nt * 16 + l16];

        floatx4 acc[4][4];
        #pragma unroll
        for (int mt = 0; mt < 4; ++mt)
            #pragma unroll
            for (int nt = 0; nt < 4; ++nt)
                acc[mt][nt] = (floatx4){0.f, 0.f, 0.f, 0.f};
        #pragma unroll
        for (int s = 0; s < 2; ++s)
            #pragma unroll
            for (int mt = 0; mt < 4; ++mt)
                #pragma unroll
                for (int nt = 0; nt < 4; ++nt)
                    acc[mt][nt] = __builtin_amdgcn_mfma_f32_16x16x32_bf16(
                        af[s][mt], bfr[s][nt], acc[mt][nt], 0, 0, 0);

        #pragma unroll
        for (int nt = 0; nt < 4; ++nt) {
            int nloc = wn * 64 + nt * 16 + l16;
            int j = jbase + nloc;
            bool jv = (j < N);
            float d2 = dn[nt];
            #pragma unroll
            for (int mt = 0; mt < 4; ++mt) {
                floatx4 a4 = acc[mt][nt];
                float t_0 = fmaf(a4[0], -2.f, d2), t_1 = fmaf(a4[1], -2.f, d2);
                float t_2 = fmaf(a4[2], -2.f, d2), t_3 = fmaf(a4[3], -2.f, d2);
                bool p0 = t_0 <= slim[mt][0], p1 = t_1 <= slim[mt][1];
                bool p2 = t_2 <= slim[mt][2], p3 = t_3 <= slim[mt][3];
                if (jv && (p0 | p1 | p2 | p3)) {
                    #pragma unroll
                    for (int rg = 0; rg < 4; ++rg) {
                        float tv = (rg == 0) ? t_0 : (rg == 1) ? t_1 : (rg == 2) ? t_2 : t_3;
                        bool pp  = (rg == 0) ? p0 : (rg == 1) ? p1 : (rg == 2) ? p2 : p3;
                        if (pp) {
                            int mloc = wm * 64 + mt * 16 + quad * 4 + rg;
                            int pos = atomicAdd(&lcnt[mloc], 1);
                            float sqb = tv + sXN[mloc];
                            if (pos < LCAP) {
                                lbd[mloc][pos] = sqb;
                                lbj[mloc][pos] = j;
                            } else {                       // rare overflow, still correct
                                int row = m0 + mloc;
                                int gp = atomicAdd(&cnt[row], 1);
                                if (gp < CAP) {
                                    bufd[(size_t)row * CAP + gp] = sqb;
                                    bufi[(size_t)row * CAP + gp] = j;
                                }
                            }
                        }
                    }
                }
            }
        }
    }
    __syncthreads();
    if (tid < 128) {
        int c = lcnt[tid];
        if (c > LCAP) c = LCAP;
        if (c > 0) {
            int row = m0 + tid;
            int base = atomicAdd(&cnt[row], c);
            for (int i = 0; i < c; ++i) {
                int gp = base + i;
                if (gp < CAP) {
                    bufd[(size_t)row * CAP + gp] = lbd[tid][i];
                    bufi[(size_t)row * CAP + gp] = lbj[tid][i];
                }
            }
        }
    }
}

// --------------------------------------------------------- select + finish --
__global__ __launch_bounds__(64) void select_finish(const float* __restrict__ bufd,
                                                    const int* __restrict__ bufi,
                                                    const int* __restrict__ cnt,
                                                    const float* __restrict__ xs,
                                                    const float* __restrict__ xnorm,
                                                    const float* __restrict__ dnorm,
                                                    const float* __restrict__ data,
                                                    const float* __restrict__ xdot,
                                                    const float* __restrict__ vel,
                                                    float* __restrict__ out) {
    __shared__ float sd[CAP];
    __shared__ int   si[CAP];
    __shared__ float sx[64];
    __shared__ float se[SSEL];
    __shared__ int   sj[SSEL];
    __shared__ int   hist[256];
    __shared__ int   s_bin, s_rank, scnt;
    __shared__ float seld[KK];
    __shared__ int   seli[KK];
    __shared__ float selw[KK];
    int row = blockIdx.x, lane = threadIdx.x;
    int n = cnt[row];
    if (n > CAP) n = CAP;
    for (int i = lane; i < n; i += 64) {
        sd[i] = bufd[(size_t)row * CAP + i];
        si[i] = bufi[(size_t)row * CAP + i];
    }
    sx[lane] = xs[row * 64 + lane];
    if (lane == 0) scnt = 0;
    __syncthreads();

    // radix: T = 20th smallest approx sq in bucket
    int rank = KK - 1;
    unsigned prefix = 0, pmask = 0;
    for (int round = 0; round < 4; ++round) {
        int shift = 24 - 8 * round;
        #pragma unroll
        for (int i = 0; i < 4; ++i) hist[lane + i * 64] = 0;
        __syncthreads();
        for (int i = lane; i < n; i += 64) {
            unsigned k = __float_as_uint(fmaxf(sd[i], 0.f));
            if ((k & pmask) == prefix) atomicAdd(&hist[(k >> shift) & 255], 1);
        }
        __syncthreads();
        {
            int base = lane * 4;
            int h0 = hist[base], h1 = hist[base + 1], h2 = hist[base + 2], h3 = hist[base + 3];
            int s4 = h0 + h1 + h2 + h3;
            int incl = s4;
            #pragma unroll
            for (int o = 1; o < 64; o <<= 1) {
                int t = __shfl_up(incl, o, 64);
                if (lane >= o) incl += t;
            }
            int excl = incl - s4;
            if (rank >= excl && rank < incl) {
                int r = rank - excl; int b = 0;
                if (r >= h0) { r -= h0; b = 1;
                    if (r >= h1) { r -= h1; b = 2;
                        if (r >= h2) { r -= h2; b = 3; } } }
                s_bin = base + b; s_rank = r;
            }
        }
        __syncthreads();
        prefix |= ((unsigned)s_bin) << shift;
        pmask  |= 0xFFu << shift;
        rank = s_rank;
    }
    float T = __uint_as_float(prefix);

    // band {approx <= T + 2*SLACK} is a superset of the exact top-20
    for (int i = lane; i < n; i += 64) {
        if (sd[i] <= T + 2.0f * SLACK) {
            int q = atomicAdd(&scnt, 1);
            if (q < SSEL) sj[q] = si[i];
        }
    }
    __syncthreads();
    int m = scnt < SSEL ? scnt : SSEL;
    // exact fp32 recompute (bit-identical chain to reference semantics used
    // since R3: sequential fmaf, k ascending)
    for (int c = lane; c < m; c += 64) {
        int j = sj[c];
        const float4* dp = reinterpret_cast<const float4*>(data + (size_t)j * 64);
        float dot = 0.f;
        #pragma unroll
        for (int kb = 0; kb < 16; ++kb) {
            float4 q = dp[kb];
            dot = fmaf(sx[kb * 4 + 0], q.x, dot);
            dot = fmaf(sx[kb * 4 + 1], q.y, dot);
            dot = fmaf(sx[kb * 4 + 2], q.z, dot);
            dot = fmaf(sx[kb * 4 + 3], q.w, dot);
        }
        se[c] = xnorm[row] + dnorm[j] - 2.0f * dot;
    }
    __syncthreads();
    // exact top-20, tie-break smaller index (matches lax.top_k)
    for (int k = 0; k < KK; ++k) {
        float v = INF_F; int id = 0x7fffffff; int p = -1;
        for (int i = lane; i < m; i += 64) {
            float x = se[i]; int xi = sj[i];
            if (x < v || (x == v && xi < id)) { v = x; id = xi; p = i; }
        }
        #pragma unroll
        for (int o = 32; o > 0; o >>= 1) {
            float ov = __shfl_xor(v, o, 64);
            int oid = __shfl_xor(id, o, 64);
            int op  = __shfl_xor(p, o, 64);
            if (ov < v || (ov == v && oid < id)) { v = ov; id = oid; p = op; }
        }
        if (lane == 0) {
            seld[k] = v; seli[k] = id;
            if (p >= 0) se[p] = INF_F;
        }
        __syncthreads();
    }
    float d20 = sqrtf(fmaxf(seld[KK - 1], 1e-30f));
    float h = fmaxf(d20, 1e-12f);
    float wk = 0.f;
    if (lane < KK) {
        float dd = sqrtf(fmaxf(seld[lane], 1e-30f));
        wk = expf(-(dd * dd) / (2.f * h * h));
    }
    float tot = wsum64(wk) + 1e-12f;
    if (lane < KK) selw[lane] = wk / tot;
    __syncthreads();
    float u = 0.f;
    #pragma unroll
    for (int k = 0; k < KK; ++k)
        u = fmaf(selw[k], vel[(size_t)seli[k] * 64 + lane], u);
    float xd = xdot[(size_t)row * 64 + lane];
    float du  = wsum64(u * xd);
    float nu2 = wsum64(u * u);
    float nx2 = wsum64(xd * xd);
    float l2  = wsum64((u - xd) * (u - xd));
    float nu = fmaxf(sqrtf(nu2), 1e-8f);
    float nx = fmaxf(sqrtf(nx2), 1e-8f);
    out[(size_t)row * 66 + lane] = xd;
    if (lane == 0) {
        out[(size_t)row * 66 + 64] = 1.f - du / (nu * nx);
        out[(size_t)row * 66 + 65] = l2;
    }
}

// ---------------------------------------------------------------------------
extern "C" void kernel_launch(void* const* d_in, const int* in_sizes, int n_in,
                              void* d_out, int out_size, void* d_ws, size_t ws_size,
                              hipStream_t stream) {
    const float* t_   = (const float*)d_in[0];
    const float* z    = (const float*)d_in[1];
    const float* data = (const float*)d_in[2];
    const float* vel  = (const float*)d_in[3];
    const float* W1   = (const float*)d_in[4];
    const float* b1   = (const float*)d_in[5];
    const float* W2   = (const float*)d_in[6];
    const float* b2   = (const float*)d_in[7];
    float* out = (float*)d_out;

    // workspace layout (floats, 16B-aligned)
    float*  xs    = (float*)d_ws;                     // 131072
    float*  xnorm = xs + 131072;                      // 2048
    float*  thr   = xnorm + 2048;                     // 2048
    int*    cnt   = (int*)(thr + 2048);               // 2048
    float*  xdot  = (float*)(cnt + 2048);             // 131072
    float*  dnorm = xdot + 131072;                    // 100096
    __bf16* xs_h  = (__bf16*)(dnorm + NPAD);          // 131072 bf16
    __bf16* d_hi  = xs_h + 131072;                    // NPAD*64 bf16
    float*  samp  = (float*)(d_hi + (size_t)NPAD * 64);  // 2048*4096
    float*  bufd  = samp;                             // overlap: samp dead first
    int*    bufi  = (int*)(bufd + (size_t)B * CAP);

    prep_kernel<<<B, 64, 0, stream>>>(z, xs, xnorm, xs_h, cnt);
    data_prep<<<(NPAD * 16) / 256, 256, 0, stream>>>(data, dnorm, d_hi);
    mlp_kernel<<<B / 8, 256, 0, stream>>>(z, t_, W1, b1, W2, b2, xdot);
    sample_gemm<<<dim3(B / 128, SAMPLE / 128), 256, 0, stream>>>(xs_h, d_hi, xnorm, dnorm, samp);
    thr_select<<<B, 256, 0, stream>>>(samp, thr);
    gemm_filter<<<dim3(B / 128, (NTILES + JT2 - 1) / JT2), 256, 0, stream>>>(
        xs_h, d_hi, xnorm, dnorm, thr, cnt, bufd, bufi);
    select_finish<<<B, 64, 0, stream>>>(bufd, bufi, cnt, xs, xnorm, dnorm, data,
                                        xdot, vel, out);
    (void)ws_size; (void)in_sizes; (void)n_in; (void)out_size;
}

// Round 8
// 346.674 us; speedup vs baseline: 1.3055x; 1.0813x over previous
//
#include <hip/hip_runtime.h>
#include <math.h>

// Problem constants
#define B      2048
#define N      100000
#define NPAD2  100352   // 49 * 16 * 128
#define JGRP   49
#define JT3    16       // j-tiles per gemm_filter block (compile-time)
#define DD     64
#define HH     256
#define KK     20
#define SAMPLE 4096
#define CAP    1536
#define SSEL   512
#define SLACK  1.5f
#define LCAP   32       // per-row LDS bucket slots

#define INF_F (__builtin_inff())

typedef __bf16 bf16x8 __attribute__((ext_vector_type(8)));
typedef __bf16 bf16x4 __attribute__((ext_vector_type(4)));
typedef float  floatx4 __attribute__((ext_vector_type(4)));
union U16 { uint4 u; bf16x8 v; };

__device__ __forceinline__ float wsum64(float v) {
    #pragma unroll
    for (int o = 32; o > 0; o >>= 1) v += __shfl_xor(v, o, 64);
    return v;
}

// ---------------------------------------------------------------- prep ------
__global__ __launch_bounds__(64) void prep_kernel(const float* __restrict__ z,
                                                  float* __restrict__ xs,
                                                  float* __restrict__ xnorm,
                                                  __bf16* __restrict__ xs_h,
                                                  int* __restrict__ cnt) {
    int b = blockIdx.x, d = threadIdx.x;
    float v = z[b * 66 + d];
    xs[b * 64 + d] = v;
    xs_h[b * 64 + d] = (__bf16)v;
    float s = wsum64(v * v);
    if (d == 0) xnorm[b] = s;
    if (d == 1) cnt[b] = 0;
}

// ---------------------------------------- dnorm + half-dnorm + bf16 convert -
__global__ __launch_bounds__(256) void data_prep(const float* __restrict__ data,
                                                 float* __restrict__ dnorm,
                                                 float* __restrict__ dnh,
                                                 __bf16* __restrict__ d_hi) {
    int gt = blockIdx.x * 256 + threadIdx.x;
    int j = gt >> 4;
    int l = gt & 15;
    if (j >= NPAD2) return;
    float4 v = make_float4(0.f, 0.f, 0.f, 0.f);
    if (j < N)
        v = reinterpret_cast<const float4*>(data + (size_t)j * 64)[l];
    bf16x4 o;
    o.x = (__bf16)v.x; o.y = (__bf16)v.y; o.z = (__bf16)v.z; o.w = (__bf16)v.w;
    *reinterpret_cast<bf16x4*>(d_hi + (size_t)j * 64 + l * 4) = o;
    float s = v.x * v.x + v.y * v.y + v.z * v.z + v.w * v.w;
    #pragma unroll
    for (int o2 = 1; o2 < 16; o2 <<= 1) s += __shfl_xor(s, o2, 64);
    if (l == 0) {
        dnorm[j] = (j < N) ? s : INF_F;
        dnh[j]   = (j < N) ? 0.5f * s : INF_F;   // pad cols can never pass
    }
}

// ---------------------------------------------------------------- mlp -------
__global__ __launch_bounds__(256) void mlp_kernel(const float* __restrict__ z,
                                                  const float* __restrict__ tp,
                                                  const float* __restrict__ W1,
                                                  const float* __restrict__ b1,
                                                  const float* __restrict__ W2,
                                                  const float* __restrict__ b2,
                                                  float* __restrict__ xdot) {
    __shared__ float sin_[8][65];
    __shared__ float shid[8][HH];
    int tid = threadIdx.x;
    int row0 = blockIdx.x * 8;
    float tval = tp[0];
    for (int idx = tid; idx < 8 * 64; idx += 256) {
        int r = idx >> 6, d = idx & 63;
        sin_[r][d] = z[(row0 + r) * 66 + d];
    }
    if (tid < 8) sin_[tid][64] = tval;
    __syncthreads();

    int h = tid;
    float acc[8];
    #pragma unroll
    for (int r = 0; r < 8; ++r) acc[r] = b1[h];
    for (int i = 0; i < 65; ++i) {
        float wv = W1[i * HH + h];
        #pragma unroll
        for (int r = 0; r < 8; ++r) acc[r] = fmaf(sin_[r][i], wv, acc[r]);
    }
    #pragma unroll
    for (int r = 0; r < 8; ++r) shid[r][h] = fmaxf(acc[r], 0.f);
    __syncthreads();

    int d = tid & 63, rb = tid >> 6;
    for (int rr = rb; rr < 8; rr += 4) {
        float a = b2[d];
        #pragma unroll 8
        for (int hh2 = 0; hh2 < HH; ++hh2)
            a = fmaf(shid[rr][hh2], W2[hh2 * 64 + d], a);
        xdot[(size_t)(row0 + rr) * 64 + d] = a;
    }
}

// --------------------------- approx sample GEMM (MFMA, register-direct) -----
__global__ __launch_bounds__(256) void sample_gemm(const __bf16* __restrict__ xs_h,
                                                   const __bf16* __restrict__ d_hi,
                                                   const float* __restrict__ xnorm,
                                                   const float* __restrict__ dnorm,
                                                   float* __restrict__ samp) {
    int tid = threadIdx.x;
    int m0 = blockIdx.x * 128;
    int jbase = blockIdx.y * 128;
    int wv = tid >> 6, wm = wv & 1, wn = wv >> 1;
    int lane = tid & 63, l16 = lane & 15, quad = lane >> 4;

    bf16x8 af[2][4], bfr[2][4];
    #pragma unroll
    for (int s = 0; s < 2; ++s)
        #pragma unroll
        for (int mt = 0; mt < 4; ++mt) {
            int row = m0 + wm * 64 + mt * 16 + l16;
            U16 u; u.u = reinterpret_cast<const uint4*>(xs_h + (size_t)row * 64)[s * 4 + quad];
            af[s][mt] = u.v;
        }
    #pragma unroll
    for (int s = 0; s < 2; ++s)
        #pragma unroll
        for (int nt = 0; nt < 4; ++nt) {
            int jr = jbase + wn * 64 + nt * 16 + l16;
            U16 u; u.u = reinterpret_cast<const uint4*>(d_hi + (size_t)jr * 64)[s * 4 + quad];
            bfr[s][nt] = u.v;
        }
    float dn[4], sxn[4][4];
    #pragma unroll
    for (int nt = 0; nt < 4; ++nt)
        dn[nt] = dnorm[jbase + wn * 64 + nt * 16 + l16];
    #pragma unroll
    for (int mt = 0; mt < 4; ++mt)
        #pragma unroll
        for (int rg = 0; rg < 4; ++rg)
            sxn[mt][rg] = xnorm[m0 + wm * 64 + mt * 16 + quad * 4 + rg];

    floatx4 acc[4][4];
    #pragma unroll
    for (int mt = 0; mt < 4; ++mt)
        #pragma unroll
        for (int nt = 0; nt < 4; ++nt)
            acc[mt][nt] = (floatx4){0.f, 0.f, 0.f, 0.f};
    #pragma unroll
    for (int s = 0; s < 2; ++s)
        #pragma unroll
        for (int mt = 0; mt < 4; ++mt)
            #pragma unroll
            for (int nt = 0; nt < 4; ++nt)
                acc[mt][nt] = __builtin_amdgcn_mfma_f32_16x16x32_bf16(
                    af[s][mt], bfr[s][nt], acc[mt][nt], 0, 0, 0);

    #pragma unroll
    for (int mt = 0; mt < 4; ++mt)
        #pragma unroll
        for (int nt = 0; nt < 4; ++nt) {
            floatx4 a4 = acc[mt][nt];
            int j = jbase + wn * 64 + nt * 16 + l16;
            #pragma unroll
            for (int rg = 0; rg < 4; ++rg) {
                int row = m0 + wm * 64 + mt * 16 + quad * 4 + rg;
                samp[(size_t)row * SAMPLE + j] = fmaf(a4[rg], -2.f, dn[nt]) + sxn[mt][rg];
            }
        }
}

// ------------------------------------------- thr select via radix-select ----
__global__ __launch_bounds__(256) void thr_select(const float* __restrict__ samp,
                                                  float* __restrict__ thr) {
    __shared__ unsigned keys[SAMPLE];
    __shared__ int hist[256];
    __shared__ int s_bin, s_rank;
    int row = blockIdx.x, tid = threadIdx.x;
    for (int i = tid; i < SAMPLE; i += 256)
        keys[i] = __float_as_uint(fmaxf(samp[(size_t)row * SAMPLE + i], 0.f));
    int rank = KK - 1;
    unsigned prefix = 0, pmask = 0;
    for (int round = 0; round < 4; ++round) {
        int shift = 24 - 8 * round;
        hist[tid] = 0;
        __syncthreads();
        for (int i = tid; i < SAMPLE; i += 256) {
            unsigned k = keys[i];
            if ((k & pmask) == prefix) atomicAdd(&hist[(k >> shift) & 255], 1);
        }
        __syncthreads();
        if (tid < 64) {
            int base = tid * 4;
            int h0 = hist[base], h1 = hist[base + 1], h2 = hist[base + 2], h3 = hist[base + 3];
            int s4 = h0 + h1 + h2 + h3;
            int incl = s4;
            #pragma unroll
            for (int o = 1; o < 64; o <<= 1) {
                int t = __shfl_up(incl, o, 64);
                if (tid >= o) incl += t;
            }
            int excl = incl - s4;
            if (rank >= excl && rank < incl) {
                int r = rank - excl; int b = 0;
                if (r >= h0) { r -= h0; b = 1;
                    if (r >= h1) { r -= h1; b = 2;
                        if (r >= h2) { r -= h2; b = 3; } } }
                s_bin = base + b; s_rank = r;
            }
        }
        __syncthreads();
        prefix |= ((unsigned)s_bin) << shift;
        pmask  |= 0xFFu << shift;
        rank = s_rank;
    }
    if (tid == 0) thr[row] = __uint_as_float(prefix);
}

// ------ bf16 MFMA filter: register double-buffered, threshold in acc init ---
// pass <=> D' >= dnh[j], where D' = dot_b + 0.5*(thr+2*SLACK-xn)
// (equivalent to sq_b <= thr + 2*SLACK; same guarantee chain as before)
__global__ __launch_bounds__(256, 2) void gemm_filter(const __bf16* __restrict__ xs_h,
                                                      const __bf16* __restrict__ d_hi,
                                                      const float* __restrict__ xnorm,
                                                      const float* __restrict__ dnh,
                                                      const float* __restrict__ thr,
                                                      int* __restrict__ cnt,
                                                      float* __restrict__ bufd,
                                                      int* __restrict__ bufi) {
    __shared__ float sc[128];            // 0.5*(thr+2S-xn)
    __shared__ float sts[128];           // thr+2S
    __shared__ int   lcnt[128];
    __shared__ float lbd[128][LCAP + 1]; // +1: break stride-32 bank aliasing
    __shared__ int   lbj[128][LCAP + 1];
    int tid = threadIdx.x;
    int m0 = blockIdx.x * 128;
    int jstart = blockIdx.y * (JT3 * 128);
    int wv = tid >> 6, wm = wv & 1, wn = wv >> 1;
    int lane = tid & 63, l16 = lane & 15, quad = lane >> 4;

    if (tid < 128) {
        float t2 = thr[m0 + tid] + 2.0f * SLACK;
        sts[tid] = t2;
        sc[tid] = 0.5f * (t2 - xnorm[m0 + tid]);
        lcnt[tid] = 0;
    }
    // persistent A fragments
    bf16x8 af[2][4];
    #pragma unroll
    for (int s = 0; s < 2; ++s)
        #pragma unroll
        for (int mt = 0; mt < 4; ++mt) {
            int row = m0 + wm * 64 + mt * 16 + l16;
            U16 u; u.u = reinterpret_cast<const uint4*>(xs_h + (size_t)row * 64)[s * 4 + quad];
            af[s][mt] = u.v;
        }
    __syncthreads();

    uint4 bb[2][8];
    float dh[2][4];
    {   // prefetch tile 0
        int jb = jstart;
        #pragma unroll
        for (int s = 0; s < 2; ++s)
            #pragma unroll
            for (int nt = 0; nt < 4; ++nt) {
                int jr = jb + wn * 64 + nt * 16 + l16;
                bb[0][s * 4 + nt] = reinterpret_cast<const uint4*>(d_hi + (size_t)jr * 64)[s * 4 + quad];
            }
        #pragma unroll
        for (int nt = 0; nt < 4; ++nt)
            dh[0][nt] = dnh[jb + wn * 64 + nt * 16 + l16];
    }

    #pragma unroll 2
    for (int t = 0; t < JT3; ++t) {
        int cur = t & 1, nxt = cur ^ 1;
        if (t + 1 < JT3) {               // prefetch next tile (covers MFMA+epilogue)
            int jb = jstart + (t + 1) * 128;
            #pragma unroll
            for (int s = 0; s < 2; ++s)
                #pragma unroll
                for (int nt = 0; nt < 4; ++nt) {
                    int jr = jb + wn * 64 + nt * 16 + l16;
                    bb[nxt][s * 4 + nt] = reinterpret_cast<const uint4*>(d_hi + (size_t)jr * 64)[s * 4 + quad];
                }
            #pragma unroll
            for (int nt = 0; nt < 4; ++nt)
                dh[nxt][nt] = dnh[jb + wn * 64 + nt * 16 + l16];
        }

        floatx4 acc[4][4];
        #pragma unroll
        for (int mt = 0; mt < 4; ++mt) {
            float4 cv = *reinterpret_cast<const float4*>(&sc[wm * 64 + mt * 16 + quad * 4]);
            #pragma unroll
            for (int nt = 0; nt < 4; ++nt)
                acc[mt][nt] = (floatx4){cv.x, cv.y, cv.z, cv.w};
        }
        #pragma unroll
        for (int s = 0; s < 2; ++s)
            #pragma unroll
            for (int mt = 0; mt < 4; ++mt)
                #pragma unroll
                for (int nt = 0; nt < 4; ++nt) {
                    U16 u; u.u = bb[cur][s * 4 + nt];
                    acc[mt][nt] = __builtin_amdgcn_mfma_f32_16x16x32_bf16(
                        af[s][mt], u.v, acc[mt][nt], 0, 0, 0);
                }

        int jb = jstart + t * 128;
        #pragma unroll
        for (int nt = 0; nt < 4; ++nt) {
            int nloc = wn * 64 + nt * 16 + l16;
            int j = jb + nloc;
            float dd = dh[cur][nt];      // INF for pad cols -> never pass
            #pragma unroll
            for (int mt = 0; mt < 4; ++mt) {
                floatx4 a4 = acc[mt][nt];
                bool p0 = a4[0] >= dd, p1 = a4[1] >= dd;
                bool p2 = a4[2] >= dd, p3 = a4[3] >= dd;
                if (p0 | p1 | p2 | p3) {
                    #pragma unroll
                    for (int rg = 0; rg < 4; ++rg) {
                        bool pp = (rg == 0) ? p0 : (rg == 1) ? p1 : (rg == 2) ? p2 : p3;
                        if (pp) {
                            int mloc = wm * 64 + mt * 16 + quad * 4 + rg;
                            float delta = 2.0f * (dd - a4[rg]);  // sqb - (thr+2S)
                            int pos = atomicAdd(&lcnt[mloc], 1);
                            if (pos < LCAP) {
                                lbd[mloc][pos] = delta;
                                lbj[mloc][pos] = j;
                            } else {                              // rare overflow
                                int row = m0 + mloc;
                                int gp = atomicAdd(&cnt[row], 1);
                                if (gp < CAP) {
                                    bufd[(size_t)row * CAP + gp] = sts[mloc] + delta;
                                    bufi[(size_t)row * CAP + gp] = j;
                                }
                            }
                        }
                    }
                }
            }
        }
    }
    __syncthreads();
    if (tid < 128) {
        int c = lcnt[tid];
        if (c > LCAP) c = LCAP;
        if (c > 0) {
            int row = m0 + tid;
            float ts = sts[tid];
            int base = atomicAdd(&cnt[row], c);
            for (int i = 0; i < c; ++i) {
                int gp = base + i;
                if (gp < CAP) {
                    bufd[(size_t)row * CAP + gp] = ts + lbd[tid][i];
                    bufi[(size_t)row * CAP + gp] = lbj[tid][i];
                }
            }
        }
    }
}

// --------------------------------------------------------- select + finish --
__global__ __launch_bounds__(64) void select_finish(const float* __restrict__ bufd,
                                                    const int* __restrict__ bufi,
                                                    const int* __restrict__ cnt,
                                                    const float* __restrict__ xs,
                                                    const float* __restrict__ xnorm,
                                                    const float* __restrict__ dnorm,
                                                    const float* __restrict__ data,
                                                    const float* __restrict__ xdot,
                                                    const float* __restrict__ vel,
                                                    float* __restrict__ out) {
    __shared__ float sd[CAP];
    __shared__ int   si[CAP];
    __shared__ float sx[64];
    __shared__ float se[SSEL];
    __shared__ int   sj[SSEL];
    __shared__ int   hist[256];
    __shared__ int   s_bin, s_rank, scnt;
    __shared__ float seld[KK];
    __shared__ int   seli[KK];
    __shared__ float selw[KK];
    int row = blockIdx.x, lane = threadIdx.x;
    int n = cnt[row];
    if (n > CAP) n = CAP;
    for (int i = lane; i < n; i += 64) {
        sd[i] = bufd[(size_t)row * CAP + i];
        si[i] = bufi[(size_t)row * CAP + i];
    }
    sx[lane] = xs[row * 64 + lane];
    if (lane == 0) scnt = 0;
    __syncthreads();

    // radix: T = 20th smallest approx sq in bucket
    int rank = KK - 1;
    unsigned prefix = 0, pmask = 0;
    for (int round = 0; round < 4; ++round) {
        int shift = 24 - 8 * round;
        #pragma unroll
        for (int i = 0; i < 4; ++i) hist[lane + i * 64] = 0;
        __syncthreads();
        for (int i = lane; i < n; i += 64) {
            unsigned k = __float_as_uint(fmaxf(sd[i], 0.f));
            if ((k & pmask) == prefix) atomicAdd(&hist[(k >> shift) & 255], 1);
        }
        __syncthreads();
        {
            int base = lane * 4;
            int h0 = hist[base], h1 = hist[base + 1], h2 = hist[base + 2], h3 = hist[base + 3];
            int s4 = h0 + h1 + h2 + h3;
            int incl = s4;
            #pragma unroll
            for (int o = 1; o < 64; o <<= 1) {
                int t = __shfl_up(incl, o, 64);
                if (lane >= o) incl += t;
            }
            int excl = incl - s4;
            if (rank >= excl && rank < incl) {
                int r = rank - excl; int b = 0;
                if (r >= h0) { r -= h0; b = 1;
                    if (r >= h1) { r -= h1; b = 2;
                        if (r >= h2) { r -= h2; b = 3; } } }
                s_bin = base + b; s_rank = r;
            }
        }
        __syncthreads();
        prefix |= ((unsigned)s_bin) << shift;
        pmask  |= 0xFFu << shift;
        rank = s_rank;
    }
    float T = __uint_as_float(prefix);

    // band {approx <= T + 2*SLACK} is a superset of the exact top-20
    for (int i = lane; i < n; i += 64) {
        if (sd[i] <= T + 2.0f * SLACK) {
            int q = atomicAdd(&scnt, 1);
            if (q < SSEL) sj[q] = si[i];
        }
    }
    __syncthreads();
    int m = scnt < SSEL ? scnt : SSEL;
    // exact fp32 recompute (bit-identical chain: sequential fmaf, k ascending)
    for (int c = lane; c < m; c += 64) {
        int j = sj[c];
        const float4* dp = reinterpret_cast<const float4*>(data + (size_t)j * 64);
        float dot = 0.f;
        #pragma unroll
        for (int kb = 0; kb < 16; ++kb) {
            float4 q = dp[kb];
            dot = fmaf(sx[kb * 4 + 0], q.x, dot);
            dot = fmaf(sx[kb * 4 + 1], q.y, dot);
            dot = fmaf(sx[kb * 4 + 2], q.z, dot);
            dot = fmaf(sx[kb * 4 + 3], q.w, dot);
        }
        se[c] = xnorm[row] + dnorm[j] - 2.0f * dot;
    }
    __syncthreads();
    // exact top-20, tie-break smaller index (matches lax.top_k)
    for (int k = 0; k < KK; ++k) {
        float v = INF_F; int id = 0x7fffffff; int p = -1;
        for (int i = lane; i < m; i += 64) {
            float x = se[i]; int xi = sj[i];
            if (x < v || (x == v && xi < id)) { v = x; id = xi; p = i; }
        }
        #pragma unroll
        for (int o = 32; o > 0; o >>= 1) {
            float ov = __shfl_xor(v, o, 64);
            int oid = __shfl_xor(id, o, 64);
            int op  = __shfl_xor(p, o, 64);
            if (ov < v || (ov == v && oid < id)) { v = ov; id = oid; p = op; }
        }
        if (lane == 0) {
            seld[k] = v; seli[k] = id;
            if (p >= 0) se[p] = INF_F;
        }
        __syncthreads();
    }
    float d20 = sqrtf(fmaxf(seld[KK - 1], 1e-30f));
    float h = fmaxf(d20, 1e-12f);
    float wk = 0.f;
    if (lane < KK) {
        float dd = sqrtf(fmaxf(seld[lane], 1e-30f));
        wk = expf(-(dd * dd) / (2.f * h * h));
    }
    float tot = wsum64(wk) + 1e-12f;
    if (lane < KK) selw[lane] = wk / tot;
    __syncthreads();
    float u = 0.f;
    #pragma unroll
    for (int k = 0; k < KK; ++k)
        u = fmaf(selw[k], vel[(size_t)seli[k] * 64 + lane], u);
    float xd = xdot[(size_t)row * 64 + lane];
    float du  = wsum64(u * xd);
    float nu2 = wsum64(u * u);
    float nx2 = wsum64(xd * xd);
    float l2  = wsum64((u - xd) * (u - xd));
    float nu = fmaxf(sqrtf(nu2), 1e-8f);
    float nx = fmaxf(sqrtf(nx2), 1e-8f);
    out[(size_t)row * 66 + lane] = xd;
    if (lane == 0) {
        out[(size_t)row * 66 + 64] = 1.f - du / (nu * nx);
        out[(size_t)row * 66 + 65] = l2;
    }
}

// ---------------------------------------------------------------------------
extern "C" void kernel_launch(void* const* d_in, const int* in_sizes, int n_in,
                              void* d_out, int out_size, void* d_ws, size_t ws_size,
                              hipStream_t stream) {
    const float* t_   = (const float*)d_in[0];
    const float* z    = (const float*)d_in[1];
    const float* data = (const float*)d_in[2];
    const float* vel  = (const float*)d_in[3];
    const float* W1   = (const float*)d_in[4];
    const float* b1   = (const float*)d_in[5];
    const float* W2   = (const float*)d_in[6];
    const float* b2   = (const float*)d_in[7];
    float* out = (float*)d_out;

    // workspace layout (floats, 16B-aligned)
    float*  xs    = (float*)d_ws;                     // 131072
    float*  xnorm = xs + 131072;                      // 2048
    float*  thr   = xnorm + 2048;                     // 2048
    int*    cnt   = (int*)(thr + 2048);               // 2048
    float*  xdot  = (float*)(cnt + 2048);             // 131072
    float*  dnorm = xdot + 131072;                    // 100352
    float*  dnh   = dnorm + NPAD2;                    // 100352
    __bf16* xs_h  = (__bf16*)(dnh + NPAD2);           // 131072 bf16
    __bf16* d_hi  = xs_h + 131072;                    // NPAD2*64 bf16
    float*  samp  = (float*)(d_hi + (size_t)NPAD2 * 64); // 2048*4096
    float*  bufd  = samp;                             // overlap: samp dead first
    int*    bufi  = (int*)(bufd + (size_t)B * CAP);

    prep_kernel<<<B, 64, 0, stream>>>(z, xs, xnorm, xs_h, cnt);
    data_prep<<<(NPAD2 * 16) / 256, 256, 0, stream>>>(data, dnorm, dnh, d_hi);
    mlp_kernel<<<B / 8, 256, 0, stream>>>(z, t_, W1, b1, W2, b2, xdot);
    sample_gemm<<<dim3(B / 128, SAMPLE / 128), 256, 0, stream>>>(xs_h, d_hi, xnorm, dnorm, samp);
    thr_select<<<B, 256, 0, stream>>>(samp, thr);
    gemm_filter<<<dim3(B / 128, JGRP), 256, 0, stream>>>(
        xs_h, d_hi, xnorm, dnh, thr, cnt, bufd, bufi);
    select_finish<<<B, 64, 0, stream>>>(bufd, bufi, cnt, xs, xnorm, dnorm, data,
                                        xdot, vel, out);
    (void)ws_size; (void)in_sizes; (void)n_in; (void)out_size;
}

// Round 9
// 299.509 us; speedup vs baseline: 1.5111x; 1.1575x over previous
//
#include <hip/hip_runtime.h>
#include <math.h>

// Problem constants
#define B      2048
#define N      100000
#define NPAD2  100352   // 98 * 1024
#define JGRP2  98
#define JT4    16       // 64-col j-steps per filter block (16*64 = 1024 cols)
#define DD     64
#define HH     256
#define KK     20
#define SAMPLE 8192
#define CAP    1024
#define SSEL   512
#define SLACK  1.5f
#define LCAP   16       // per-row LDS bucket slots (lambda ~2.7 per block)

#define INF_F (__builtin_inff())

typedef __bf16 bf16x8 __attribute__((ext_vector_type(8)));
typedef __bf16 bf16x4 __attribute__((ext_vector_type(4)));
typedef float  floatx4 __attribute__((ext_vector_type(4)));
union U16 { uint4 u; bf16x8 v; };

__device__ __forceinline__ float wsum64(float v) {
    #pragma unroll
    for (int o = 32; o > 0; o >>= 1) v += __shfl_xor(v, o, 64);
    return v;
}
__device__ __forceinline__ int wsum64i(int v) {
    #pragma unroll
    for (int o = 32; o > 0; o >>= 1) v += __shfl_xor(v, o, 64);
    return v;
}

// ---------------- fused setup: data_prep + prep + mlp (block-range dispatch) -
// blocks [0, 6272)            : data_prep (dnorm, dnh, d_hi)
// blocks [6272, 6784)         : prep (xs, xnorm, xs_h, cnt=0), 4 rows/block
// blocks [6784, 7040)         : mlp, 8 rows/block
#define NB_DATA 6272
#define NB_PREP 512
#define NB_MLP  256
__global__ __launch_bounds__(256) void setup_all(const float* __restrict__ z,
                                                 const float* __restrict__ tp,
                                                 const float* __restrict__ data,
                                                 const float* __restrict__ W1,
                                                 const float* __restrict__ b1,
                                                 const float* __restrict__ W2,
                                                 const float* __restrict__ b2,
                                                 float* __restrict__ xs,
                                                 float* __restrict__ xnorm,
                                                 __bf16* __restrict__ xs_h,
                                                 int* __restrict__ cnt,
                                                 float* __restrict__ dnorm,
                                                 float* __restrict__ dnh,
                                                 __bf16* __restrict__ d_hi,
                                                 float* __restrict__ xdot) {
    int bx = blockIdx.x, tid = threadIdx.x;
    if (bx < NB_DATA) {
        int gt = bx * 256 + tid;
        int j = gt >> 4, l = gt & 15;
        float4 v = make_float4(0.f, 0.f, 0.f, 0.f);
        if (j < N)
            v = reinterpret_cast<const float4*>(data + (size_t)j * 64)[l];
        bf16x4 o;
        o.x = (__bf16)v.x; o.y = (__bf16)v.y; o.z = (__bf16)v.z; o.w = (__bf16)v.w;
        *reinterpret_cast<bf16x4*>(d_hi + (size_t)j * 64 + l * 4) = o;
        float s = v.x * v.x + v.y * v.y + v.z * v.z + v.w * v.w;
        #pragma unroll
        for (int o2 = 1; o2 < 16; o2 <<= 1) s += __shfl_xor(s, o2, 64);
        if (l == 0) {
            dnorm[j] = (j < N) ? s : INF_F;
            dnh[j]   = (j < N) ? 0.5f * s : INF_F;
        }
    } else if (bx < NB_DATA + NB_PREP) {
        int row = (bx - NB_DATA) * 4 + (tid >> 6);
        int d = tid & 63;
        float v = z[row * 66 + d];
        xs[row * 64 + d] = v;
        xs_h[row * 64 + d] = (__bf16)v;
        float s = wsum64(v * v);
        if (d == 0) xnorm[row] = s;
        if (d == 1) cnt[row] = 0;
    } else {
        __shared__ float sin_[8][65];
        __shared__ float shid[8][HH];
        int row0 = (bx - NB_DATA - NB_PREP) * 8;
        float tval = tp[0];
        for (int idx = tid; idx < 8 * 64; idx += 256) {
            int r = idx >> 6, d = idx & 63;
            sin_[r][d] = z[(row0 + r) * 66 + d];
        }
        if (tid < 8) sin_[tid][64] = tval;
        __syncthreads();
        int h = tid;
        float acc[8];
        #pragma unroll
        for (int r = 0; r < 8; ++r) acc[r] = b1[h];
        for (int i = 0; i < 65; ++i) {
            float wv = W1[i * HH + h];
            #pragma unroll
            for (int r = 0; r < 8; ++r) acc[r] = fmaf(sin_[r][i], wv, acc[r]);
        }
        #pragma unroll
        for (int r = 0; r < 8; ++r) shid[r][h] = fmaxf(acc[r], 0.f);
        __syncthreads();
        int d = tid & 63, rb = tid >> 6;
        for (int rr = rb; rr < 8; rr += 4) {
            float a = b2[d];
            #pragma unroll 8
            for (int hh2 = 0; hh2 < HH; ++hh2)
                a = fmaf(shid[rr][hh2], W2[hh2 * 64 + d], a);
            xdot[(size_t)(row0 + rr) * 64 + d] = a;
        }
    }
}

// --------------------- approx sample GEMM -> u16 keys (top 16 bits of fp32) -
__global__ __launch_bounds__(256) void sample_gemm(const __bf16* __restrict__ xs_h,
                                                   const __bf16* __restrict__ d_hi,
                                                   const float* __restrict__ xnorm,
                                                   const float* __restrict__ dnorm,
                                                   unsigned short* __restrict__ samp16) {
    int tid = threadIdx.x;
    int m0 = blockIdx.x * 128;
    int jbase = blockIdx.y * 128;
    int wv = tid >> 6, wm = wv & 1, wn = wv >> 1;
    int lane = tid & 63, l16 = lane & 15, quad = lane >> 4;

    bf16x8 af[2][4], bfr[2][4];
    #pragma unroll
    for (int s = 0; s < 2; ++s)
        #pragma unroll
        for (int mt = 0; mt < 4; ++mt) {
            int row = m0 + wm * 64 + mt * 16 + l16;
            U16 u; u.u = reinterpret_cast<const uint4*>(xs_h + (size_t)row * 64)[s * 4 + quad];
            af[s][mt] = u.v;
        }
    #pragma unroll
    for (int s = 0; s < 2; ++s)
        #pragma unroll
        for (int nt = 0; nt < 4; ++nt) {
            int jr = jbase + wn * 64 + nt * 16 + l16;
            U16 u; u.u = reinterpret_cast<const uint4*>(d_hi + (size_t)jr * 64)[s * 4 + quad];
            bfr[s][nt] = u.v;
        }
    float dn[4], sxn[4][4];
    #pragma unroll
    for (int nt = 0; nt < 4; ++nt)
        dn[nt] = dnorm[jbase + wn * 64 + nt * 16 + l16];
    #pragma unroll
    for (int mt = 0; mt < 4; ++mt)
        #pragma unroll
        for (int rg = 0; rg < 4; ++rg)
            sxn[mt][rg] = xnorm[m0 + wm * 64 + mt * 16 + quad * 4 + rg];

    floatx4 acc[4][4];
    #pragma unroll
    for (int mt = 0; mt < 4; ++mt)
        #pragma unroll
        for (int nt = 0; nt < 4; ++nt)
            acc[mt][nt] = (floatx4){0.f, 0.f, 0.f, 0.f};
    #pragma unroll
    for (int s = 0; s < 2; ++s)
        #pragma unroll
        for (int mt = 0; mt < 4; ++mt)
            #pragma unroll
            for (int nt = 0; nt < 4; ++nt)
                acc[mt][nt] = __builtin_amdgcn_mfma_f32_16x16x32_bf16(
                    af[s][mt], bfr[s][nt], acc[mt][nt], 0, 0, 0);

    #pragma unroll
    for (int mt = 0; mt < 4; ++mt)
        #pragma unroll
        for (int nt = 0; nt < 4; ++nt) {
            floatx4 a4 = acc[mt][nt];
            int j = jbase + wn * 64 + nt * 16 + l16;
            #pragma unroll
            for (int rg = 0; rg < 4; ++rg) {
                int row = m0 + wm * 64 + mt * 16 + quad * 4 + rg;
                float sq = fmaf(a4[rg], -2.f, dn[nt]) + sxn[mt][rg];
                samp16[(size_t)row * SAMPLE + j] =
                    (unsigned short)(__float_as_uint(fmaxf(sq, 0.f)) >> 16);
            }
        }
}

// --------------- thr select: one wave per row, bitwise bisection on u16 keys
// thr = float bits ((k20+1)<<16) -- ceiling of the 20th-smallest key's bin,
// an upper bound on the 20th-smallest approx sample sq. Safe: chain only
// needs thr >= (20th approx sample sq) - 0; ceiling only loosens.
__global__ __launch_bounds__(256) void thr_select(const unsigned short* __restrict__ samp16,
                                                  float* __restrict__ thr) {
    int wv = threadIdx.x >> 6, lane = threadIdx.x & 63;
    int row = blockIdx.x * 4 + wv;
    const unsigned* sp = reinterpret_cast<const unsigned*>(samp16 + (size_t)row * SAMPLE);
    unsigned w[64];
    #pragma unroll
    for (int i = 0; i < 64; ++i) w[i] = sp[lane + i * 64];
    unsigned res = 0;
    for (int b = 15; b >= 0; --b) {
        unsigned cand = res | (1u << b);
        int c = 0;
        #pragma unroll
        for (int i = 0; i < 64; ++i) {
            c += ((w[i] & 0xFFFFu) < cand);
            c += ((w[i] >> 16) < cand);
        }
        c = wsum64i(c);
        if (c <= KK - 1) res = cand;   // rank 19 (0-indexed) = 20th smallest
    }
    if (lane == 0) thr[row] = __uint_as_float((res + 1u) << 16);
}

// ------ bf16 MFMA filter: 64x32 wave tile, register double-buffer, 64-col
// steps. pass <=> D >= dnh[j] with D = dot_b + 0.5*(thr+2S-xn)
// (equivalent to sq_b <= thr + 2*SLACK; same guarantee chain as R7/R8)
__global__ __launch_bounds__(256, 3) void gemm_filter(const __bf16* __restrict__ xs_h,
                                                      const __bf16* __restrict__ d_hi,
                                                      const float* __restrict__ xnorm,
                                                      const float* __restrict__ dnh,
                                                      const float* __restrict__ thr,
                                                      int* __restrict__ cnt,
                                                      float* __restrict__ bufd,
                                                      int* __restrict__ bufi) {
    __shared__ float sts[128];           // thr+2S
    __shared__ int   lcnt[128];
    __shared__ float lbd[128][LCAP + 1];
    __shared__ int   lbj[128][LCAP + 1];
    int tid = threadIdx.x;
    int m0 = blockIdx.x * 128;
    int jstart = blockIdx.y * (JT4 * 64);
    int wv = tid >> 6, wm = wv & 1, wn = wv >> 1;   // 2x2 wave grid
    int lane = tid & 63, l16 = lane & 15, quad = lane >> 4;

    if (tid < 128) {
        sts[tid] = thr[m0 + tid] + 2.0f * SLACK;
        lcnt[tid] = 0;
    }
    // persistent A fragments
    bf16x8 af[2][4];
    #pragma unroll
    for (int s = 0; s < 2; ++s)
        #pragma unroll
        for (int mt = 0; mt < 4; ++mt) {
            int row = m0 + wm * 64 + mt * 16 + l16;
            U16 u; u.u = reinterpret_cast<const uint4*>(xs_h + (size_t)row * 64)[s * 4 + quad];
            af[s][mt] = u.v;
        }
    // acc-init constants: 0.5*(thr+2S-xn) per (mt,rg)
    float scv[4][4];
    #pragma unroll
    for (int mt = 0; mt < 4; ++mt)
        #pragma unroll
        for (int rg = 0; rg < 4; ++rg) {
            int mg = m0 + wm * 64 + mt * 16 + quad * 4 + rg;
            scv[mt][rg] = 0.5f * (thr[mg] + 2.0f * SLACK - xnorm[mg]);
        }
    __syncthreads();

    uint4 bb[2][4];   // [buf][s*2+nt]
    float dh[2][2];
    {   // prefetch step 0
        #pragma unroll
        for (int s = 0; s < 2; ++s)
            #pragma unroll
            for (int nt = 0; nt < 2; ++nt) {
                int jr = jstart + wn * 32 + nt * 16 + l16;
                bb[0][s * 2 + nt] = reinterpret_cast<const uint4*>(d_hi + (size_t)jr * 64)[s * 4 + quad];
            }
        #pragma unroll
        for (int nt = 0; nt < 2; ++nt)
            dh[0][nt] = dnh[jstart + wn * 32 + nt * 16 + l16];
    }

    #pragma unroll 2
    for (int t = 0; t < JT4; ++t) {
        int cur = t & 1, nxt = cur ^ 1;
        if (t + 1 < JT4) {               // prefetch next step
            int jb = jstart + (t + 1) * 64;
            #pragma unroll
            for (int s = 0; s < 2; ++s)
                #pragma unroll
                for (int nt = 0; nt < 2; ++nt) {
                    int jr = jb + wn * 32 + nt * 16 + l16;
                    bb[nxt][s * 2 + nt] = reinterpret_cast<const uint4*>(d_hi + (size_t)jr * 64)[s * 4 + quad];
                }
            #pragma unroll
            for (int nt = 0; nt < 2; ++nt)
                dh[nxt][nt] = dnh[jb + wn * 32 + nt * 16 + l16];
        }

        floatx4 acc[4][2];
        #pragma unroll
        for (int mt = 0; mt < 4; ++mt) {
            floatx4 cv = (floatx4){scv[mt][0], scv[mt][1], scv[mt][2], scv[mt][3]};
            acc[mt][0] = cv;
            acc[mt][1] = cv;
        }
        #pragma unroll
        for (int s = 0; s < 2; ++s) {
            U16 u0, u1;
            u0.u = bb[cur][s * 2 + 0];
            u1.u = bb[cur][s * 2 + 1];
            #pragma unroll
            for (int mt = 0; mt < 4; ++mt) {
                acc[mt][0] = __builtin_amdgcn_mfma_f32_16x16x32_bf16(af[s][mt], u0.v, acc[mt][0], 0, 0, 0);
                acc[mt][1] = __builtin_amdgcn_mfma_f32_16x16x32_bf16(af[s][mt], u1.v, acc[mt][1], 0, 0, 0);
            }
        }

        int jb = jstart + t * 64;
        #pragma unroll
        for (int nt = 0; nt < 2; ++nt) {
            int j = jb + wn * 32 + nt * 16 + l16;
            float dd = dh[cur][nt];      // INF for pad cols -> never pass
            #pragma unroll
            for (int mt = 0; mt < 4; ++mt) {
                floatx4 a4 = acc[mt][nt];
                bool p0 = a4[0] >= dd, p1 = a4[1] >= dd;
                bool p2 = a4[2] >= dd, p3 = a4[3] >= dd;
                if (p0 | p1 | p2 | p3) {
                    #pragma unroll
                    for (int rg = 0; rg < 4; ++rg) {
                        bool pp = (rg == 0) ? p0 : (rg == 1) ? p1 : (rg == 2) ? p2 : p3;
                        if (pp) {
                            int mloc = wm * 64 + mt * 16 + quad * 4 + rg;
                            float delta = 2.0f * (dd - a4[rg]);  // sqb - (thr+2S)
                            int pos = atomicAdd(&lcnt[mloc], 1);
                            if (pos < LCAP) {
                                lbd[mloc][pos] = delta;
                                lbj[mloc][pos] = j;
                            } else {                              // rare overflow
                                int row = m0 + mloc;
                                int gp = atomicAdd(&cnt[row], 1);
                                if (gp < CAP) {
                                    bufd[(size_t)row * CAP + gp] = sts[mloc] + delta;
                                    bufi[(size_t)row * CAP + gp] = j;
                                }
                            }
                        }
                    }
                }
            }
        }
    }
    __syncthreads();
    if (tid < 128) {
        int c = lcnt[tid];
        if (c > LCAP) c = LCAP;
        if (c > 0) {
            int row = m0 + tid;
            float ts = sts[tid];
            int base = atomicAdd(&cnt[row], c);
            for (int i = 0; i < c; ++i) {
                int gp = base + i;
                if (gp < CAP) {
                    bufd[(size_t)row * CAP + gp] = ts + lbd[tid][i];
                    bufi[(size_t)row * CAP + gp] = lbj[tid][i];
                }
            }
        }
    }
}

// --------------------------------------------------------- select + finish --
__global__ __launch_bounds__(64) void select_finish(const float* __restrict__ bufd,
                                                    const int* __restrict__ bufi,
                                                    const int* __restrict__ cnt,
                                                    const float* __restrict__ xs,
                                                    const float* __restrict__ xnorm,
                                                    const float* __restrict__ dnorm,
                                                    const float* __restrict__ data,
                                                    const float* __restrict__ xdot,
                                                    const float* __restrict__ vel,
                                                    float* __restrict__ out) {
    __shared__ float sd[CAP];
    __shared__ int   si[CAP];
    __shared__ float sx[64];
    __shared__ float se[SSEL];
    __shared__ int   sj[SSEL];
    __shared__ int   scnt;
    __shared__ float seld[KK];
    __shared__ int   seli[KK];
    __shared__ float selw[KK];
    int row = blockIdx.x, lane = threadIdx.x;
    int n = cnt[row];
    if (n > CAP) n = CAP;
    for (int i = lane; i < n; i += 64) {
        sd[i] = bufd[(size_t)row * CAP + i];
        si[i] = bufi[(size_t)row * CAP + i];
    }
    sx[lane] = xs[row * 64 + lane];
    if (lane == 0) scnt = 0;
    __syncthreads();

    // T = exact 20th smallest of clamped approx sq -- bitwise bisection
    unsigned res = 0;
    for (int b = 30; b >= 0; --b) {
        unsigned cand = res | (1u << b);
        int c = 0;
        for (int i = lane; i < n; i += 64)
            c += (__float_as_uint(fmaxf(sd[i], 0.f)) < cand);
        c = wsum64i(c);
        if (c <= KK - 1) res = cand;
    }
    float T = __uint_as_float(res);

    // band {approx <= T + 2*SLACK} is a superset of the exact top-20
    for (int i = lane; i < n; i += 64) {
        if (sd[i] <= T + 2.0f * SLACK) {
            int q = atomicAdd(&scnt, 1);
            if (q < SSEL) sj[q] = si[i];
        }
    }
    __syncthreads();
    int m = scnt < SSEL ? scnt : SSEL;
    // exact fp32 recompute (bit-identical chain: sequential fmaf, k ascending)
    for (int c = lane; c < m; c += 64) {
        int j = sj[c];
        const float4* dp = reinterpret_cast<const float4*>(data + (size_t)j * 64);
        float dot = 0.f;
        #pragma unroll
        for (int kb = 0; kb < 16; ++kb) {
            float4 q = dp[kb];
            dot = fmaf(sx[kb * 4 + 0], q.x, dot);
            dot = fmaf(sx[kb * 4 + 1], q.y, dot);
            dot = fmaf(sx[kb * 4 + 2], q.z, dot);
            dot = fmaf(sx[kb * 4 + 3], q.w, dot);
        }
        se[c] = xnorm[row] + dnorm[j] - 2.0f * dot;
    }
    __syncthreads();
    // exact top-20, tie-break smaller index (matches lax.top_k)
    for (int k = 0; k < KK; ++k) {
        float v = INF_F; int id = 0x7fffffff; int p = -1;
        for (int i = lane; i < m; i += 64) {
            float x = se[i]; int xi = sj[i];
            if (x < v || (x == v && xi < id)) { v = x; id = xi; p = i; }
        }
        #pragma unroll
        for (int o = 32; o > 0; o >>= 1) {
            float ov = __shfl_xor(v, o, 64);
            int oid = __shfl_xor(id, o, 64);
            int op  = __shfl_xor(p, o, 64);
            if (ov < v || (ov == v && oid < id)) { v = ov; id = oid; p = op; }
        }
        if (lane == 0) {
            seld[k] = v; seli[k] = id;
            if (p >= 0) se[p] = INF_F;
        }
        __syncthreads();
    }
    float d20 = sqrtf(fmaxf(seld[KK - 1], 1e-30f));
    float h = fmaxf(d20, 1e-12f);
    float wk = 0.f;
    if (lane < KK) {
        float dd = sqrtf(fmaxf(seld[lane], 1e-30f));
        wk = expf(-(dd * dd) / (2.f * h * h));
    }
    float tot = wsum64(wk) + 1e-12f;
    if (lane < KK) selw[lane] = wk / tot;
    __syncthreads();
    float u = 0.f;
    #pragma unroll
    for (int k = 0; k < KK; ++k)
        u = fmaf(selw[k], vel[(size_t)seli[k] * 64 + lane], u);
    float xd = xdot[(size_t)row * 64 + lane];
    float du  = wsum64(u * xd);
    float nu2 = wsum64(u * u);
    float nx2 = wsum64(xd * xd);
    float l2  = wsum64((u - xd) * (u - xd));
    float nu = fmaxf(sqrtf(nu2), 1e-8f);
    float nx = fmaxf(sqrtf(nx2), 1e-8f);
    out[(size_t)row * 66 + lane] = xd;
    if (lane == 0) {
        out[(size_t)row * 66 + 64] = 1.f - du / (nu * nx);
        out[(size_t)row * 66 + 65] = l2;
    }
}

// ---------------------------------------------------------------------------
extern "C" void kernel_launch(void* const* d_in, const int* in_sizes, int n_in,
                              void* d_out, int out_size, void* d_ws, size_t ws_size,
                              hipStream_t stream) {
    const float* t_   = (const float*)d_in[0];
    const float* z    = (const float*)d_in[1];
    const float* data = (const float*)d_in[2];
    const float* vel  = (const float*)d_in[3];
    const float* W1   = (const float*)d_in[4];
    const float* b1   = (const float*)d_in[5];
    const float* W2   = (const float*)d_in[6];
    const float* b2   = (const float*)d_in[7];
    float* out = (float*)d_out;

    // workspace layout (floats, 16B-aligned); total ~47 MB
    float*  xs    = (float*)d_ws;                     // 131072
    float*  xnorm = xs + 131072;                      // 2048
    float*  thr   = xnorm + 2048;                     // 2048
    int*    cnt   = (int*)(thr + 2048);               // 2048
    float*  xdot  = (float*)(cnt + 2048);             // 131072
    float*  dnorm = xdot + 131072;                    // 100352
    float*  dnh   = dnorm + NPAD2;                    // 100352
    __bf16* xs_h  = (__bf16*)(dnh + NPAD2);           // 131072 bf16
    __bf16* d_hi  = xs_h + 131072;                    // NPAD2*64 bf16
    unsigned short* samp16 = (unsigned short*)(d_hi + (size_t)NPAD2 * 64); // 2048*8192 u16 = 32MB
    float*  bufd  = (float*)samp16;                   // overlap: samp16 dead first
    int*    bufi  = (int*)(bufd + (size_t)B * CAP);   // 2048*1024

    setup_all<<<NB_DATA + NB_PREP + NB_MLP, 256, 0, stream>>>(
        z, t_, data, W1, b1, W2, b2, xs, xnorm, xs_h, cnt, dnorm, dnh, d_hi, xdot);
    sample_gemm<<<dim3(B / 128, SAMPLE / 128), 256, 0, stream>>>(xs_h, d_hi, xnorm, dnorm, samp16);
    thr_select<<<B / 4, 256, 0, stream>>>(samp16, thr);
    gemm_filter<<<dim3(B / 128, JGRP2), 256, 0, stream>>>(
        xs_h, d_hi, xnorm, dnh, thr, cnt, bufd, bufi);
    select_finish<<<B, 64, 0, stream>>>(bufd, bufi, cnt, xs, xnorm, dnorm, data,
                                        xdot, vel, out);
    (void)ws_size; (void)in_sizes; (void)n_in; (void)out_size;
}